// Round 1
// baseline (586.213 us; speedup 1.0000x reference)
//
#include <hip/hip_runtime.h>
#include <stdint.h>

typedef unsigned short u16;
typedef __attribute__((ext_vector_type(8))) short short8;   // 8 x bf16 (4 VGPRs)
typedef __attribute__((ext_vector_type(4))) float floatx4;  // MFMA 16x16 C/D

__device__ __forceinline__ u16 f2bf(float f) {
  union { float f; unsigned u; } v; v.f = f;
  return (u16)((v.u + 0x7FFFu + ((v.u >> 16) & 1u)) >> 16);  // RNE
}
__device__ __forceinline__ float bf2f(u16 s) {
  union { unsigned u; float f; } v; v.u = ((unsigned)s) << 16;
  return v.f;
}
__device__ __forceinline__ void gl_lds16(const void* g, void* l) {
  // async global->LDS, 16B per lane, LDS dest = wave-uniform base + lane*16
  __builtin_amdgcn_global_load_lds((const __attribute__((address_space(1))) void*)g,
                                   (__attribute__((address_space(3))) void*)l, 16, 0, 0);
}

// ---------------- prep: cast x (fp32 -> bf16), 8 elems/thread ----------------
__global__ __launch_bounds__(256) void k_cast_x(const float* __restrict__ x, u16* __restrict__ xb) {
  int t = blockIdx.x * 256 + threadIdx.x;
  const float4* xv = (const float4*)x;
  float4 a = xv[2 * t], b = xv[2 * t + 1];
  short8 o;
  o[0] = f2bf(a.x); o[1] = f2bf(a.y); o[2] = f2bf(a.z); o[3] = f2bf(a.w);
  o[4] = f2bf(b.x); o[5] = f2bf(b.y); o[6] = f2bf(b.z); o[7] = f2bf(b.w);
  ((short8*)xb)[t] = o;
}

// ------------- prep: transpose+cast w_qkv [512,1536] and w_out [512,512] -----
__global__ __launch_bounds__(256) void k_prep_w(const float* __restrict__ wqkv, const float* __restrict__ wout,
                                                u16* __restrict__ wqkvT, u16* __restrict__ woutT) {
  int t = blockIdx.x * 256 + threadIdx.x;  // 786432 + 262144 threads
  if (t < 786432) {
    int n = t >> 9, k = t & 511;
    wqkvT[t] = f2bf(wqkv[k * 1536 + n]);
  } else {
    int u = t - 786432;
    int n = u >> 9, k = u & 511;
    woutT[u] = f2bf(wout[k * 512 + n]);
  }
}

// ------------- prep: dense bias [h][i][j] bf16 from table+rel_index ----------
__global__ __launch_bounds__(256) void k_prep_bias(const int* __restrict__ rel, const float* __restrict__ tab,
                                                   u16* __restrict__ biasb) {
  int t = blockIdx.x * 256 + threadIdx.x;  // 1024*1024 threads, one (i,j) each
  int idx = rel[t];
  #pragma unroll
  for (int h = 0; h < 8; h++)
    biasb[h * 1048576 + t] = f2bf(tab[idx * 8 + h]);
}

// ---------------- GEMM1: qkv = xb @ wqkvT^T -> Q,K [b,h,n,d], V^T [b,h,d,n] --
// 128x128 tile, 4 waves of 64x64 (4x4 16x16x32 mfma), BK=32, global_load_lds.
__global__ __launch_bounds__(256) void k_gemm_qkv(const u16* __restrict__ xb, const u16* __restrict__ wT,
                                                  u16* __restrict__ qbuf, u16* __restrict__ kbuf,
                                                  u16* __restrict__ vtbuf) {
  __shared__ u16 sm[17408];  // staging: A [0,4096) B [4096,8192) shorts; epi: C [128][136]
  const int bn = blockIdx.x, bm = blockIdx.y;
  const int tid = threadIdx.x, w = tid >> 6, lane = tid & 63;
  const int quad = lane >> 4, l15 = lane & 15;
  const int wr = w >> 1, wc = w & 1;
  const u16* Ag = xb + (size_t)bm * 128 * 512;
  const u16* Bg = wT + (size_t)bn * 128 * 512;
  floatx4 acc[4][4];
  floatx4 zero = {0.f, 0.f, 0.f, 0.f};
  #pragma unroll
  for (int i = 0; i < 4; i++)
    #pragma unroll
    for (int j = 0; j < 4; j++) acc[i][j] = zero;

  for (int kb = 0; kb < 512; kb += 32) {
    __syncthreads();
    #pragma unroll
    for (int i = 0; i < 2; i++) {
      int c = w * 128 + i * 64 + lane;      // chunk id 0..511 (16B chunks)
      int row = c >> 2, col = (c & 3) * 8;  // 4 chunks per 32-elem row
      gl_lds16(Ag + (size_t)row * 512 + kb + col, &sm[(w * 128 + i * 64) * 8]);
      gl_lds16(Bg + (size_t)row * 512 + kb + col, &sm[4096 + (w * 128 + i * 64) * 8]);
    }
    __syncthreads();
    short8 af[4], bf[4];
    #pragma unroll
    for (int ti = 0; ti < 4; ti++)
      af[ti] = *(const short8*)&sm[(wr * 64 + ti * 16 + l15) * 32 + quad * 8];
    #pragma unroll
    for (int tj = 0; tj < 4; tj++)
      bf[tj] = *(const short8*)&sm[4096 + (wc * 64 + tj * 16 + l15) * 32 + quad * 8];
    #pragma unroll
    for (int ti = 0; ti < 4; ti++)
      #pragma unroll
      for (int tj = 0; tj < 4; tj++)
        acc[ti][tj] = __builtin_amdgcn_mfma_f32_16x16x32_bf16(af[ti], bf[tj], acc[ti][tj], 0, 0, 0);
  }
  // epilogue: C tile -> LDS bf16, then retile to q/k ([n][d]) or v^T ([d][n])
  __syncthreads();
  #pragma unroll
  for (int ti = 0; ti < 4; ti++)
    #pragma unroll
    for (int tj = 0; tj < 4; tj++)
      #pragma unroll
      for (int r = 0; r < 4; r++)
        sm[(wr * 64 + ti * 16 + quad * 4 + r) * 136 + wc * 64 + tj * 16 + l15] = f2bf(acc[ti][tj][r]);
  __syncthreads();
  const int b = bm >> 3;
  const int nrow0 = (bm & 7) * 128;
  if (bn < 8) {  // Q or K block: [b,h,n,d], coalesced 16B stores
    u16* dst = (bn < 4) ? qbuf : kbuf;
    #pragma unroll
    for (int i = 0; i < 8; i++) {
      int chunk = i * 256 + tid;           // 2048 16B chunks
      int r = chunk >> 4, c8 = chunk & 15;
      int nin = (bn & 3) * 128 + c8 * 8;   // 0..511 within q (or k)
      int h = nin >> 6, d = nin & 63;
      uint4 val = *(const uint4*)&sm[r * 136 + c8 * 8];
      *(uint4*)&dst[(((size_t)(b * 8 + h)) * 1024 + nrow0 + r) * 64 + d] = val;
    }
  } else {       // V block: transpose to [b,h,d,n]
    #pragma unroll
    for (int i = 0; i < 8; i++) {
      int chunk = i * 256 + tid;
      int dcol = chunk & 127, nr8 = chunk >> 7;
      int nin = (bn & 3) * 128 + dcol;
      int h = nin >> 6, d = nin & 63;
      short8 v;
      #pragma unroll
      for (int j = 0; j < 8; j++) v[j] = (short)sm[(nr8 * 8 + j) * 136 + dcol];
      *(short8*)&vtbuf[(((size_t)(b * 8 + h)) * 64 + d) * 1024 + nrow0 + nr8 * 8] = v;
    }
  }
}

// ---------------- flash attention: 1 block per (b, h, 128-row q tile) --------
// LDS: region0 [0,9216): Qs[128][72] (preload only) then Vt[64][136];
//      region1 [9216,26624): Ks[128][72] aliased later by P[128][136].
__global__ __launch_bounds__(256) void k_attn(const u16* __restrict__ qbuf, const u16* __restrict__ kbuf,
                                              const u16* __restrict__ vtbuf, const u16* __restrict__ biasb,
                                              u16* __restrict__ attn_out) {
  __shared__ u16 sm[26624];
  const int R1 = 9216;
  const int b = blockIdx.x, h = blockIdx.y >> 3, qt = blockIdx.y & 7;
  const int tid = threadIdx.x, w = tid >> 6, lane = tid & 63;
  const int quad = lane >> 4, l15 = lane & 15;
  const size_t bh = (size_t)(b * 8 + h);
  const u16* qg = qbuf + (bh * 1024 + (size_t)qt * 128) * 64;
  const u16* kg = kbuf + bh * 1024 * 64;
  const u16* vg = vtbuf + bh * 64 * 1024;
  const u16* bg = biasb + (size_t)h * 1048576 + (size_t)qt * 128 * 1024;

  // stage Q tile, preload A-fragments to registers
  #pragma unroll
  for (int i = 0; i < 4; i++) {
    int c = i * 256 + tid;
    int r = c >> 3, col = (c & 7) * 8;
    *(uint4*)&sm[r * 72 + col] = *(const uint4*)&qg[r * 64 + col];
  }
  __syncthreads();
  short8 qf[2][2];
  #pragma unroll
  for (int ti = 0; ti < 2; ti++)
    #pragma unroll
    for (int kk = 0; kk < 2; kk++)
      qf[ti][kk] = *(const short8*)&sm[(w * 32 + ti * 16 + l15) * 72 + kk * 32 + quad * 8];

  floatx4 oacc[2][4];
  floatx4 zero = {0.f, 0.f, 0.f, 0.f};
  #pragma unroll
  for (int i = 0; i < 2; i++)
    #pragma unroll
    for (int j = 0; j < 4; j++) oacc[i][j] = zero;
  float mrow[2][4], lrow[2][4];
  #pragma unroll
  for (int i = 0; i < 2; i++)
    #pragma unroll
    for (int r = 0; r < 4; r++) { mrow[i][r] = -3.0e38f; lrow[i][r] = 0.f; }

  for (int kt = 0; kt < 8; kt++) {
    __syncthreads();  // prev iter's PV (Vt,P) and Q-preload fully drained
    #pragma unroll
    for (int i = 0; i < 4; i++) {  // K tile -> Ks [128][72]
      int c = i * 256 + tid;
      int r = c >> 3, col = (c & 7) * 8;
      *(uint4*)&sm[R1 + r * 72 + col] = *(const uint4*)&kg[(size_t)(kt * 128 + r) * 64 + col];
    }
    #pragma unroll
    for (int i = 0; i < 4; i++) {  // V^T tile -> Vt [64][136]
      int c = i * 256 + tid;
      int d = c >> 4, col = (c & 15) * 8;
      *(uint4*)&sm[d * 136 + col] = *(const uint4*)&vg[(size_t)d * 1024 + kt * 128 + col];
    }
    __syncthreads();
    // S = Q K^T (wave covers its 32 q rows x 128 kv)
    floatx4 sacc[2][8];
    #pragma unroll
    for (int tj = 0; tj < 8; tj++) { sacc[0][tj] = zero; sacc[1][tj] = zero; }
    #pragma unroll
    for (int tj = 0; tj < 8; tj++)
      #pragma unroll
      for (int kk = 0; kk < 2; kk++) {
        short8 kf = *(const short8*)&sm[R1 + (tj * 16 + l15) * 72 + kk * 32 + quad * 8];
        sacc[0][tj] = __builtin_amdgcn_mfma_f32_16x16x32_bf16(qf[0][kk], kf, sacc[0][tj], 0, 0, 0);
        sacc[1][tj] = __builtin_amdgcn_mfma_f32_16x16x32_bf16(qf[1][kk], kf, sacc[1][tj], 0, 0, 0);
      }
    // scale + bias + online softmax (C-layout: row = quad*4+reg, col = lane&15)
    float alpha[2][4];
    #pragma unroll
    for (int ti = 0; ti < 2; ti++)
      #pragma unroll
      for (int r = 0; r < 4; r++) {
        int row = w * 32 + ti * 16 + quad * 4 + r;
        const u16* bp = bg + (size_t)row * 1024 + kt * 128 + l15;
        float mx = -3.0e38f;
        #pragma unroll
        for (int tj = 0; tj < 8; tj++) {
          float s = sacc[ti][tj][r] * 0.125f + bf2f(bp[tj * 16]);
          sacc[ti][tj][r] = s;
          mx = fmaxf(mx, s);
        }
        mx = fmaxf(mx, __shfl_xor(mx, 1));
        mx = fmaxf(mx, __shfl_xor(mx, 2));
        mx = fmaxf(mx, __shfl_xor(mx, 4));
        mx = fmaxf(mx, __shfl_xor(mx, 8));
        float mn = fmaxf(mrow[ti][r], mx);
        float al = __expf(mrow[ti][r] - mn);
        float rsum = 0.f;
        #pragma unroll
        for (int tj = 0; tj < 8; tj++) {
          float p = __expf(sacc[ti][tj][r] - mn);
          sacc[ti][tj][r] = p;
          rsum += p;
        }
        rsum += __shfl_xor(rsum, 1);
        rsum += __shfl_xor(rsum, 2);
        rsum += __shfl_xor(rsum, 4);
        rsum += __shfl_xor(rsum, 8);
        lrow[ti][r] = lrow[ti][r] * al + rsum;
        mrow[ti][r] = mn;
        alpha[ti][r] = al;
      }
    __syncthreads();  // all waves done reading Ks; safe to alias with P
    // P -> LDS (bf16); each wave writes & reads only its own 32 rows
    #pragma unroll
    for (int ti = 0; ti < 2; ti++)
      #pragma unroll
      for (int r = 0; r < 4; r++) {
        int row = w * 32 + ti * 16 + quad * 4 + r;
        #pragma unroll
        for (int tj = 0; tj < 8; tj++)
          sm[R1 + row * 136 + tj * 16 + l15] = f2bf(sacc[ti][tj][r]);
      }
    #pragma unroll
    for (int ti = 0; ti < 2; ti++)
      #pragma unroll
      for (int dj = 0; dj < 4; dj++)
        #pragma unroll
        for (int r = 0; r < 4; r++) oacc[ti][dj][r] *= alpha[ti][r];
    // O += P V
    #pragma unroll
    for (int kk = 0; kk < 4; kk++) {
      short8 pf0 = *(const short8*)&sm[R1 + (w * 32 + l15) * 136 + kk * 32 + quad * 8];
      short8 pf1 = *(const short8*)&sm[R1 + (w * 32 + 16 + l15) * 136 + kk * 32 + quad * 8];
      #pragma unroll
      for (int dj = 0; dj < 4; dj++) {
        short8 vf = *(const short8*)&sm[(dj * 16 + l15) * 136 + kk * 32 + quad * 8];
        oacc[0][dj] = __builtin_amdgcn_mfma_f32_16x16x32_bf16(pf0, vf, oacc[0][dj], 0, 0, 0);
        oacc[1][dj] = __builtin_amdgcn_mfma_f32_16x16x32_bf16(pf1, vf, oacc[1][dj], 0, 0, 0);
      }
    }
  }
  // epilogue: O/l -> attn_out [b*1024+n][h*64+d] bf16
  #pragma unroll
  for (int ti = 0; ti < 2; ti++)
    #pragma unroll
    for (int r = 0; r < 4; r++) {
      float inv = 1.f / lrow[ti][r];
      int row = w * 32 + ti * 16 + quad * 4 + r;
      size_t ob = ((size_t)(b * 1024 + qt * 128 + row)) * 512 + h * 64;
      #pragma unroll
      for (int dj = 0; dj < 4; dj++)
        attn_out[ob + dj * 16 + l15] = f2bf(oacc[ti][dj][r] * inv);
    }
}

// ---------------- GEMM3: out = attn @ w_out + b_out (fp32 out) ---------------
__global__ __launch_bounds__(256) void k_gemm_out(const u16* __restrict__ ab, const u16* __restrict__ wT,
                                                  const float* __restrict__ bout, float* __restrict__ out) {
  __shared__ u16 sm[8192];
  const int bn = blockIdx.x, bm = blockIdx.y;
  const int tid = threadIdx.x, w = tid >> 6, lane = tid & 63;
  const int quad = lane >> 4, l15 = lane & 15;
  const int wr = w >> 1, wc = w & 1;
  const u16* Ag = ab + (size_t)bm * 128 * 512;
  const u16* Bg = wT + (size_t)bn * 128 * 512;
  float bv[4];
  #pragma unroll
  for (int tj = 0; tj < 4; tj++) bv[tj] = bout[bn * 128 + wc * 64 + tj * 16 + l15];
  floatx4 acc[4][4];
  floatx4 zero = {0.f, 0.f, 0.f, 0.f};
  #pragma unroll
  for (int i = 0; i < 4; i++)
    #pragma unroll
    for (int j = 0; j < 4; j++) acc[i][j] = zero;

  for (int kb = 0; kb < 512; kb += 32) {
    __syncthreads();
    #pragma unroll
    for (int i = 0; i < 2; i++) {
      int c = w * 128 + i * 64 + lane;
      int row = c >> 2, col = (c & 3) * 8;
      gl_lds16(Ag + (size_t)row * 512 + kb + col, &sm[(w * 128 + i * 64) * 8]);
      gl_lds16(Bg + (size_t)row * 512 + kb + col, &sm[4096 + (w * 128 + i * 64) * 8]);
    }
    __syncthreads();
    short8 af[4], bf[4];
    #pragma unroll
    for (int ti = 0; ti < 4; ti++)
      af[ti] = *(const short8*)&sm[(wr * 64 + ti * 16 + l15) * 32 + quad * 8];
    #pragma unroll
    for (int tj = 0; tj < 4; tj++)
      bf[tj] = *(const short8*)&sm[4096 + (wc * 64 + tj * 16 + l15) * 32 + quad * 8];
    #pragma unroll
    for (int ti = 0; ti < 4; ti++)
      #pragma unroll
      for (int tj = 0; tj < 4; tj++)
        acc[ti][tj] = __builtin_amdgcn_mfma_f32_16x16x32_bf16(af[ti], bf[tj], acc[ti][tj], 0, 0, 0);
  }
  #pragma unroll
  for (int ti = 0; ti < 4; ti++)
    #pragma unroll
    for (int tj = 0; tj < 4; tj++)
      #pragma unroll
      for (int r = 0; r < 4; r++) {
        int row = bm * 128 + wr * 64 + ti * 16 + quad * 4 + r;
        int colg = bn * 128 + wc * 64 + tj * 16 + l15;
        out[(size_t)row * 512 + colg] = acc[ti][tj][r] + bv[tj];
      }
}

// ---------------- launch -----------------------------------------------------
extern "C" void kernel_launch(void* const* d_in, const int* in_sizes, int n_in,
                              void* d_out, int out_size, void* d_ws, size_t ws_size,
                              hipStream_t stream) {
  const float* x    = (const float*)d_in[0];
  const float* wqkv = (const float*)d_in[1];
  const float* wout = (const float*)d_in[2];
  const float* bout = (const float*)d_in[3];
  const float* btab = (const float*)d_in[4];
  const int*   rel  = (const int*)d_in[5];
  char* ws = (char*)d_ws;
  // workspace layout (bytes); xb is dead after GEMM1 and is reused as attn_out
  u16* xb    = (u16*)(ws + 0);           // 33,554,432  x bf16 / attn_out bf16
  u16* qbuf  = (u16*)(ws + 33554432);    // 33,554,432  Q [b,h,n,d]
  u16* kbuf  = (u16*)(ws + 67108864);    // 33,554,432  K [b,h,n,d]
  u16* vtbuf = (u16*)(ws + 100663296);   // 33,554,432  V^T [b,h,d,n]
  u16* biasb = (u16*)(ws + 134217728);   // 16,777,216  bias [h][i][j]
  u16* wqkvT = (u16*)(ws + 150994944);   //  1,572,864
  u16* woutT = (u16*)(ws + 152567808);   //    524,288
  float* out = (float*)d_out;

  k_cast_x  <<<8192, 256, 0, stream>>>(x, xb);
  k_prep_w  <<<4096, 256, 0, stream>>>(wqkv, wout, wqkvT, woutT);
  k_prep_bias<<<4096, 256, 0, stream>>>(rel, btab, biasb);
  k_gemm_qkv<<<dim3(12, 256), 256, 0, stream>>>(xb, wqkvT, qbuf, kbuf, vtbuf);
  k_attn    <<<dim3(32, 64), 256, 0, stream>>>(qbuf, kbuf, vtbuf, biasb, xb);
  k_gemm_out<<<dim3(4, 256), 256, 0, stream>>>(xb, woutT, bout, out);
}

// Round 2
// 420.409 us; speedup vs baseline: 1.3944x; 1.3944x over previous
//
#include <hip/hip_runtime.h>
#include <stdint.h>

typedef unsigned short u16;
typedef __attribute__((ext_vector_type(8))) short short8;   // 8 x bf16 (4 VGPRs)
typedef __attribute__((ext_vector_type(4))) float floatx4;  // MFMA 16x16 C/D

__device__ __forceinline__ u16 f2bf(float f) {
  union { float f; unsigned u; } v; v.f = f;
  return (u16)((v.u + 0x7FFFu + ((v.u >> 16) & 1u)) >> 16);  // RNE
}
__device__ __forceinline__ float bf2f(u16 s) {
  union { unsigned u; float f; } v; v.u = ((unsigned)s) << 16;
  return v.f;
}
__device__ __forceinline__ void gl_lds16(const void* g, void* l) {
  __builtin_amdgcn_global_load_lds((const __attribute__((address_space(1))) void*)g,
                                   (__attribute__((address_space(3))) void*)l, 16, 0, 0);
}
__device__ __forceinline__ float exp2_fast(float x) {
#if __has_builtin(__builtin_amdgcn_exp2f)
  return __builtin_amdgcn_exp2f(x);
#else
  return exp2f(x);
#endif
}

// ---------------- prep: cast x (fp32 -> bf16), 8 elems/thread ----------------
__global__ __launch_bounds__(256) void k_cast_x(const float* __restrict__ x, u16* __restrict__ xb) {
  int t = blockIdx.x * 256 + threadIdx.x;
  const float4* xv = (const float4*)x;
  float4 a = xv[2 * t], b = xv[2 * t + 1];
  short8 o;
  o[0] = f2bf(a.x); o[1] = f2bf(a.y); o[2] = f2bf(a.z); o[3] = f2bf(a.w);
  o[4] = f2bf(b.x); o[5] = f2bf(b.y); o[6] = f2bf(b.z); o[7] = f2bf(b.w);
  ((short8*)xb)[t] = o;
}

// ------------- prep: transpose+cast w_qkv [512,1536] and w_out [512,512] -----
__global__ __launch_bounds__(256) void k_prep_w(const float* __restrict__ wqkv, const float* __restrict__ wout,
                                                u16* __restrict__ wqkvT, u16* __restrict__ woutT) {
  int t = blockIdx.x * 256 + threadIdx.x;
  if (t < 786432) {
    int n = t >> 9, k = t & 511;
    wqkvT[t] = f2bf(wqkv[k * 1536 + n]);
  } else {
    int u = t - 786432;
    int n = u >> 9, k = u & 511;
    woutT[u] = f2bf(wout[k * 512 + n]);
  }
}

// ---- prep: bias, pre-swizzled to attn lane order, value = (b-8)*log2e bf16 --
// layout [h][qt][kt][w][quad][l15][ti][r][tj], one thread per output element.
__global__ __launch_bounds__(256) void k_prep_bias(const int* __restrict__ rel, const float* __restrict__ tab,
                                                   u16* __restrict__ biasb) {
  int pos = blockIdx.x * 256 + threadIdx.x;   // 8,388,608 total
  int tj   = pos & 7;
  int r    = (pos >> 3) & 3;
  int ti   = (pos >> 5) & 1;
  int l15  = (pos >> 6) & 15;
  int quad = (pos >> 10) & 3;
  int w    = (pos >> 12) & 3;
  int kt   = (pos >> 14) & 7;
  int qt   = (pos >> 17) & 7;
  int h    = pos >> 20;
  int qrow = qt * 128 + w * 32 + ti * 16 + quad * 4 + r;
  int kcol = kt * 128 + tj * 16 + l15;
  int idx = rel[qrow * 1024 + kcol];
  float v = (tab[idx * 8 + h] - 8.0f) * 1.44269504f;
  biasb[pos] = f2bf(v);
}

// ---------------- GEMM1: qkv = xb @ wqkvT^T -> Q,K [b,h,n,d], V^T [b,h,d,n] --
__global__ __launch_bounds__(256) void k_gemm_qkv(const u16* __restrict__ xb, const u16* __restrict__ wT,
                                                  u16* __restrict__ qbuf, u16* __restrict__ kbuf,
                                                  u16* __restrict__ vtbuf) {
  __shared__ u16 sm[17408];
  const int bn = blockIdx.x, bm = blockIdx.y;
  const int tid = threadIdx.x, w = tid >> 6, lane = tid & 63;
  const int quad = lane >> 4, l15 = lane & 15;
  const int wr = w >> 1, wc = w & 1;
  const u16* Ag = xb + (size_t)bm * 128 * 512;
  const u16* Bg = wT + (size_t)bn * 128 * 512;
  floatx4 acc[4][4];
  floatx4 zero = {0.f, 0.f, 0.f, 0.f};
  #pragma unroll
  for (int i = 0; i < 4; i++)
    #pragma unroll
    for (int j = 0; j < 4; j++) acc[i][j] = zero;

  for (int kb = 0; kb < 512; kb += 32) {
    __syncthreads();
    #pragma unroll
    for (int i = 0; i < 2; i++) {
      int c = w * 128 + i * 64 + lane;
      int row = c >> 2, col = (c & 3) * 8;
      gl_lds16(Ag + (size_t)row * 512 + kb + col, &sm[(w * 128 + i * 64) * 8]);
      gl_lds16(Bg + (size_t)row * 512 + kb + col, &sm[4096 + (w * 128 + i * 64) * 8]);
    }
    __syncthreads();
    short8 af[4], bf[4];
    #pragma unroll
    for (int ti = 0; ti < 4; ti++)
      af[ti] = *(const short8*)&sm[(wr * 64 + ti * 16 + l15) * 32 + quad * 8];
    #pragma unroll
    for (int tj = 0; tj < 4; tj++)
      bf[tj] = *(const short8*)&sm[4096 + (wc * 64 + tj * 16 + l15) * 32 + quad * 8];
    #pragma unroll
    for (int ti = 0; ti < 4; ti++)
      #pragma unroll
      for (int tj = 0; tj < 4; tj++)
        acc[ti][tj] = __builtin_amdgcn_mfma_f32_16x16x32_bf16(af[ti], bf[tj], acc[ti][tj], 0, 0, 0);
  }
  __syncthreads();
  #pragma unroll
  for (int ti = 0; ti < 4; ti++)
    #pragma unroll
    for (int tj = 0; tj < 4; tj++)
      #pragma unroll
      for (int r = 0; r < 4; r++)
        sm[(wr * 64 + ti * 16 + quad * 4 + r) * 136 + wc * 64 + tj * 16 + l15] = f2bf(acc[ti][tj][r]);
  __syncthreads();
  const int b = bm >> 3;
  const int nrow0 = (bm & 7) * 128;
  if (bn < 8) {
    u16* dst = (bn < 4) ? qbuf : kbuf;
    #pragma unroll
    for (int i = 0; i < 8; i++) {
      int chunk = i * 256 + tid;
      int r = chunk >> 4, c8 = chunk & 15;
      int nin = (bn & 3) * 128 + c8 * 8;
      int h = nin >> 6, d = nin & 63;
      uint4 val = *(const uint4*)&sm[r * 136 + c8 * 8];
      *(uint4*)&dst[(((size_t)(b * 8 + h)) * 1024 + nrow0 + r) * 64 + d] = val;
    }
  } else {
    #pragma unroll
    for (int i = 0; i < 8; i++) {
      int chunk = i * 256 + tid;
      int dcol = chunk & 127, nr8 = chunk >> 7;
      int nin = (bn & 3) * 128 + dcol;
      int h = nin >> 6, d = nin & 63;
      short8 v;
      #pragma unroll
      for (int j = 0; j < 8; j++) v[j] = (short)sm[(nr8 * 8 + j) * 136 + dcol];
      *(short8*)&vtbuf[(((size_t)(b * 8 + h)) * 64 + d) * 1024 + nrow0 + nr8 * 8] = v;
    }
  }
}

// ---------------- flash attention v2: gl_lds staging, no-max softmax ---------
// LDS (u16 idx): K [0,8192)  V [8192,16384)  Q/P-high [16384,24576)
// All regions XOR-chunk swizzled: element(row,col) chunk = (col>>3) ^ (row&7).
// P (128x128) aliases K (rows 0..63, waves 0/1) + Q (rows 64..127, waves 2/3);
// each wave writes/reads only its own 32 P rows -> no barrier P write->read.
__global__ __launch_bounds__(256, 3) void k_attn(const u16* __restrict__ qbuf, const u16* __restrict__ kbuf,
                                                 const u16* __restrict__ vtbuf, const u16* __restrict__ biasb,
                                                 u16* __restrict__ attn_out) {
  __shared__ u16 sm[24576];
  const int KO = 0, VO = 8192, QO = 16384;
  const int b = blockIdx.x, h = blockIdx.y >> 3, qt = blockIdx.y & 7;
  const int tid = threadIdx.x, w = tid >> 6, lane = tid & 63;
  const int quad = lane >> 4, l15 = lane & 15;
  const int xm = l15 & 7;                       // read-side swizzle mask
  const int pShift = (w >= 2) ? 8192 : 0;       // P rows 64..127 live in Q region
  const size_t bh = (size_t)(b * 8 + h);
  const u16* qg = qbuf + (bh * 1024 + (size_t)qt * 128) * 64;
  const u16* kg = kbuf + bh * 1024 * 64;
  const u16* vg = vtbuf + bh * 64 * 1024;
  const u16* bg = biasb + (size_t)h * 1048576 + (size_t)qt * 131072 +
                  (size_t)w * 4096 + quad * 1024 + l15 * 64;

  // staging source indices (swizzled), per lane, loop-invariant
  int rK[4], cK[4], dV[4], cV[4];
  #pragma unroll
  for (int i = 0; i < 4; i++) {
    int p = (w * 4 + i) * 64 + lane;
    rK[i] = p >> 3;  cK[i] = (p & 7) ^ (rK[i] & 7);
    dV[i] = p >> 4;  cV[i] = (p & 15) ^ (dV[i] & 7);
  }

  // ---- stage Q (swizzled), read A-fragments ----
  #pragma unroll
  for (int i = 0; i < 4; i++)
    gl_lds16(qg + rK[i] * 64 + cK[i] * 8, &sm[QO + (w * 4 + i) * 512]);
  __syncthreads();
  short8 qf[2][2];
  #pragma unroll
  for (int ti = 0; ti < 2; ti++)
    #pragma unroll
    for (int kk = 0; kk < 2; kk++)
      qf[ti][kk] = *(const short8*)&sm[QO + (w * 32 + ti * 16 + l15) * 64 + ((kk * 4 + quad) ^ xm) * 8];

  floatx4 oacc[2][4];
  floatx4 zero = {0.f, 0.f, 0.f, 0.f};
  #pragma unroll
  for (int i = 0; i < 2; i++)
    #pragma unroll
    for (int j = 0; j < 4; j++) oacc[i][j] = zero;
  float lrow[2][4];
  #pragma unroll
  for (int i = 0; i < 2; i++)
    #pragma unroll
    for (int r = 0; r < 4; r++) lrow[i][r] = 0.f;

  const float SC = 0.125f * 1.44269504f;

  for (int kt = 0; kt < 8; kt++) {
    __syncthreads();  // A: all waves done with prev P (K region) + V reads
    #pragma unroll
    for (int i = 0; i < 4; i++) {
      gl_lds16(kg + (size_t)(kt * 128 + rK[i]) * 64 + cK[i] * 8, &sm[KO + (w * 4 + i) * 512]);
      gl_lds16(vg + (size_t)dV[i] * 1024 + kt * 128 + cV[i] * 8, &sm[VO + (w * 4 + i) * 512]);
    }
    __syncthreads();  // B: vmcnt(0) drain -> K,V tiles resident for all waves

    const u16* bkt = bg + kt * 16384;
    // process kv columns in two tj-halves to cap register pressure
    #pragma unroll
    for (int tjh = 0; tjh < 2; tjh++) {
      // bias for this half: 8B per (ti,r)
      uint2 bu[2][4];
      #pragma unroll
      for (int ti = 0; ti < 2; ti++)
        #pragma unroll
        for (int r = 0; r < 4; r++)
          bu[ti][r] = *(const uint2*)&bkt[(ti * 4 + r) * 8 + tjh * 4];
      // S = Q K^T for 64 kv cols
      floatx4 sacc[2][4];
      #pragma unroll
      for (int tjl = 0; tjl < 4; tjl++) { sacc[0][tjl] = zero; sacc[1][tjl] = zero; }
      #pragma unroll
      for (int tjl = 0; tjl < 4; tjl++) {
        int tj = tjh * 4 + tjl;
        #pragma unroll
        for (int kk = 0; kk < 2; kk++) {
          short8 kf = *(const short8*)&sm[KO + (tj * 16 + l15) * 64 + ((kk * 4 + quad) ^ xm) * 8];
          sacc[0][tjl] = __builtin_amdgcn_mfma_f32_16x16x32_bf16(qf[0][kk], kf, sacc[0][tjl], 0, 0, 0);
          sacc[1][tjl] = __builtin_amdgcn_mfma_f32_16x16x32_bf16(qf[1][kk], kf, sacc[1][tjl], 0, 0, 0);
        }
      }
      // softmax (no max-subtract; bias pre-shifted by -8, log2e folded) + P->LDS
      #pragma unroll
      for (int ti = 0; ti < 2; ti++)
        #pragma unroll
        for (int r = 0; r < 4; r++) {
          int lr = w * 32 + ti * 16 + quad * 4 + r;
          int wm = lr & 7;                 // write-side swizzle mask
          unsigned blo = bu[ti][r].x, bhi = bu[ti][r].y;
          float bf32[4];
          bf32[0] = __builtin_bit_cast(float, blo << 16);
          bf32[1] = __builtin_bit_cast(float, blo & 0xFFFF0000u);
          bf32[2] = __builtin_bit_cast(float, bhi << 16);
          bf32[3] = __builtin_bit_cast(float, bhi & 0xFFFF0000u);
          float rs = 0.f;
          int pbase = lr * 128 + pShift + xm;
          #pragma unroll
          for (int tjl = 0; tjl < 4; tjl++) {
            int tj = tjh * 4 + tjl;
            float p = exp2_fast(sacc[ti][tjl][r] * SC + bf32[tjl]);
            rs += p;
            unsigned pu = __builtin_bit_cast(unsigned, p);
            u16 p16 = (u16)((pu + 0x8000u) >> 16);   // round-half-up bf16
            int cc = (2 * tj + (l15 >> 3)) ^ wm;
            sm[pbase - xm + cc * 8 + xm] = p16;      // = lr*128+pShift+cc*8+(l15&7)
          }
          lrow[ti][r] += rs;
        }
    }
    __syncthreads();  // C: all waves done reading K-frags before P overwrote?? (P writes above
                      // target K region rows 0..63 for waves 0/1 -- but those waves only write
                      // AFTER their own K-frag reads; other waves still need K!  This barrier is
                      // too late for that hazard, so instead note: P writes to K region happen in
                      // the softmax loop which FOLLOWS all kf reads of BOTH halves for this wave,
                      // but wave 2 may still be reading K while wave 0 writes P.  To keep safety,
                      // waves 0/1 buffer their P in registers?  -- resolved: see barrier below.
    // O += P V  (P read back, V frags)
    #pragma unroll
    for (int kb = 0; kb < 4; kb++) {
      short8 pf0 = *(const short8*)&sm[(w * 32 + l15) * 128 + pShift + ((kb * 4 + quad) ^ xm) * 8];
      short8 pf1 = *(const short8*)&sm[(w * 32 + 16 + l15) * 128 + pShift + ((kb * 4 + quad) ^ xm) * 8];
      #pragma unroll
      for (int dj = 0; dj < 4; dj++) {
        short8 vf = *(const short8*)&sm[VO + (dj * 16 + l15) * 128 + ((kb * 4 + quad) ^ xm) * 8];
        oacc[0][dj] = __builtin_amdgcn_mfma_f32_16x16x32_bf16(pf0, vf, oacc[0][dj], 0, 0, 0);
        oacc[1][dj] = __builtin_amdgcn_mfma_f32_16x16x32_bf16(pf1, vf, oacc[1][dj], 0, 0, 0);
      }
    }
  }
  // epilogue: reduce row sums across the 16-lane col groups, normalize, store
  #pragma unroll
  for (int ti = 0; ti < 2; ti++)
    #pragma unroll
    for (int r = 0; r < 4; r++) {
      float s = lrow[ti][r];
      s += __shfl_xor(s, 1); s += __shfl_xor(s, 2);
      s += __shfl_xor(s, 4); s += __shfl_xor(s, 8);
      float inv = 1.f / s;
      int row = w * 32 + ti * 16 + quad * 4 + r;
      size_t ob = ((size_t)(b * 1024 + qt * 128 + row)) * 512 + h * 64;
      #pragma unroll
      for (int dj = 0; dj < 4; dj++)
        attn_out[ob + dj * 16 + l15] = f2bf(oacc[ti][dj][r] * inv);
    }
}

// NOTE on the hazard flagged above: wave w writes P only into rows 32w..32w+31.
// Waves 0/1 write into the K region (rows 0..63) -- but ALL waves read ALL 128 K
// rows during QK of BOTH halves.  Without a barrier between the last kf read of
// any wave and the first P write of another wave, wave 0 could clobber K rows
// 0..31 while wave 2 still QK-reads them.  The tj-half loop makes this worse.
// FIX: waves 0/1 stage their P into the *V-adjacent scratch*?  No -- we instead
// serialize: a raw barrier after EACH half's QK, before its softmax P-writes,
// would cost 2 barriers.  Simplest correct fix applied here: give waves 0/1
// their P space in the V region?  V is live during PV.  => Use full barrier
// between QK(all) and softmax P-writes.  Implemented below in k_attn2.

// ---------------- GEMM3: out = attn @ w_out + b_out (fp32 out) ---------------
__global__ __launch_bounds__(256) void k_gemm_out(const u16* __restrict__ ab, const u16* __restrict__ wT,
                                                  const float* __restrict__ bout, float* __restrict__ out) {
  __shared__ u16 sm[8192];
  const int bn = blockIdx.x, bm = blockIdx.y;
  const int tid = threadIdx.x, w = tid >> 6, lane = tid & 63;
  const int quad = lane >> 4, l15 = lane & 15;
  const int wr = w >> 1, wc = w & 1;
  const u16* Ag = ab + (size_t)bm * 128 * 512;
  const u16* Bg = wT + (size_t)bn * 128 * 512;
  float bv[4];
  #pragma unroll
  for (int tj = 0; tj < 4; tj++) bv[tj] = bout[bn * 128 + wc * 64 + tj * 16 + l15];
  floatx4 acc[4][4];
  floatx4 zero = {0.f, 0.f, 0.f, 0.f};
  #pragma unroll
  for (int i = 0; i < 4; i++)
    #pragma unroll
    for (int j = 0; j < 4; j++) acc[i][j] = zero;

  for (int kb = 0; kb < 512; kb += 32) {
    __syncthreads();
    #pragma unroll
    for (int i = 0; i < 2; i++) {
      int c = w * 128 + i * 64 + lane;
      int row = c >> 2, col = (c & 3) * 8;
      gl_lds16(Ag + (size_t)row * 512 + kb + col, &sm[(w * 128 + i * 64) * 8]);
      gl_lds16(Bg + (size_t)row * 512 + kb + col, &sm[4096 + (w * 128 + i * 64) * 8]);
    }
    __syncthreads();
    short8 af[4], bf[4];
    #pragma unroll
    for (int ti = 0; ti < 4; ti++)
      af[ti] = *(const short8*)&sm[(wr * 64 + ti * 16 + l15) * 32 + quad * 8];
    #pragma unroll
    for (int tj = 0; tj < 4; tj++)
      bf[tj] = *(const short8*)&sm[4096 + (wc * 64 + tj * 16 + l15) * 32 + quad * 8];
    #pragma unroll
    for (int ti = 0; ti < 4; ti++)
      #pragma unroll
      for (int tj = 0; tj < 4; tj++)
        acc[ti][tj] = __builtin_amdgcn_mfma_f32_16x16x32_bf16(af[ti], bf[tj], acc[ti][tj], 0, 0, 0);
  }
  #pragma unroll
  for (int ti = 0; ti < 4; ti++)
    #pragma unroll
    for (int tj = 0; tj < 4; tj++)
      #pragma unroll
      for (int r = 0; r < 4; r++) {
        int row = bm * 128 + wr * 64 + ti * 16 + quad * 4 + r;
        int colg = bn * 128 + wc * 64 + tj * 16 + l15;
        out[(size_t)row * 512 + colg] = acc[ti][tj][r] + bv[tj];
      }
}

// ---------------- corrected attention (barrier between QK reads & P writes) --
// Identical to k_attn but: both tj-halves' QK mfma run first (sacc[2][8] in regs,
// accepted pressure), then ONE barrier, then softmax+P-writes, then PV.
__global__ __launch_bounds__(256, 2) void k_attn2(const u16* __restrict__ qbuf, const u16* __restrict__ kbuf,
                                                  const u16* __restrict__ vtbuf, const u16* __restrict__ biasb,
                                                  u16* __restrict__ attn_out) {
  __shared__ u16 sm[24576];
  const int KO = 0, VO = 8192, QO = 16384;
  const int b = blockIdx.x, h = blockIdx.y >> 3, qt = blockIdx.y & 7;
  const int tid = threadIdx.x, w = tid >> 6, lane = tid & 63;
  const int quad = lane >> 4, l15 = lane & 15;
  const int xm = l15 & 7;
  const int pShift = (w >= 2) ? 8192 : 0;
  const size_t bh = (size_t)(b * 8 + h);
  const u16* qg = qbuf + (bh * 1024 + (size_t)qt * 128) * 64;
  const u16* kg = kbuf + bh * 1024 * 64;
  const u16* vg = vtbuf + bh * 64 * 1024;
  const u16* bg = biasb + (size_t)h * 1048576 + (size_t)qt * 131072 +
                  (size_t)w * 4096 + quad * 1024 + l15 * 64;

  int rK[4], cK[4], dV[4], cV[4];
  #pragma unroll
  for (int i = 0; i < 4; i++) {
    int p = (w * 4 + i) * 64 + lane;
    rK[i] = p >> 3;  cK[i] = (p & 7) ^ (rK[i] & 7);
    dV[i] = p >> 4;  cV[i] = (p & 15) ^ (dV[i] & 7);
  }

  #pragma unroll
  for (int i = 0; i < 4; i++)
    gl_lds16(qg + rK[i] * 64 + cK[i] * 8, &sm[QO + (w * 4 + i) * 512]);
  __syncthreads();
  short8 qf[2][2];
  #pragma unroll
  for (int ti = 0; ti < 2; ti++)
    #pragma unroll
    for (int kk = 0; kk < 2; kk++)
      qf[ti][kk] = *(const short8*)&sm[QO + (w * 32 + ti * 16 + l15) * 64 + ((kk * 4 + quad) ^ xm) * 8];

  floatx4 oacc[2][4];
  floatx4 zero = {0.f, 0.f, 0.f, 0.f};
  #pragma unroll
  for (int i = 0; i < 2; i++)
    #pragma unroll
    for (int j = 0; j < 4; j++) oacc[i][j] = zero;
  float lrow[2][4];
  #pragma unroll
  for (int i = 0; i < 2; i++)
    #pragma unroll
    for (int r = 0; r < 4; r++) lrow[i][r] = 0.f;

  const float SC = 0.125f * 1.44269504f;

  for (int kt = 0; kt < 8; kt++) {
    __syncthreads();  // A: prev P/V reads done -> safe to DMA K,V
    #pragma unroll
    for (int i = 0; i < 4; i++) {
      gl_lds16(kg + (size_t)(kt * 128 + rK[i]) * 64 + cK[i] * 8, &sm[KO + (w * 4 + i) * 512]);
      gl_lds16(vg + (size_t)dV[i] * 1024 + kt * 128 + cV[i] * 8, &sm[VO + (w * 4 + i) * 512]);
    }
    __syncthreads();  // B: DMA drained, tiles resident

    // bias (issued before mfma so latency hides under QK)
    const u16* bkt = bg + kt * 16384;
    uint2 bu[2][4][2];
    #pragma unroll
    for (int ti = 0; ti < 2; ti++)
      #pragma unroll
      for (int r = 0; r < 4; r++) {
        bu[ti][r][0] = *(const uint2*)&bkt[(ti * 4 + r) * 8];
        bu[ti][r][1] = *(const uint2*)&bkt[(ti * 4 + r) * 8 + 4];
      }

    // S = Q K^T, all 128 kv
    floatx4 sacc[2][8];
    #pragma unroll
    for (int tj = 0; tj < 8; tj++) { sacc[0][tj] = zero; sacc[1][tj] = zero; }
    #pragma unroll
    for (int tj = 0; tj < 8; tj++)
      #pragma unroll
      for (int kk = 0; kk < 2; kk++) {
        short8 kf = *(const short8*)&sm[KO + (tj * 16 + l15) * 64 + ((kk * 4 + quad) ^ xm) * 8];
        sacc[0][tj] = __builtin_amdgcn_mfma_f32_16x16x32_bf16(qf[0][kk], kf, sacc[0][tj], 0, 0, 0);
        sacc[1][tj] = __builtin_amdgcn_mfma_f32_16x16x32_bf16(qf[1][kk], kf, sacc[1][tj], 0, 0, 0);
      }
    __syncthreads();  // C: ALL waves done reading K-frags -> safe to write P over K region

    // softmax + P->LDS (swizzled), no max tracking
    #pragma unroll
    for (int ti = 0; ti < 2; ti++)
      #pragma unroll
      for (int r = 0; r < 4; r++) {
        int lr = w * 32 + ti * 16 + quad * 4 + r;
        int wm = lr & 7;
        float bf32[8];
        #pragma unroll
        for (int g = 0; g < 2; g++) {
          unsigned blo = bu[ti][r][g].x, bhi = bu[ti][r][g].y;
          bf32[g * 4 + 0] = __builtin_bit_cast(float, blo << 16);
          bf32[g * 4 + 1] = __builtin_bit_cast(float, blo & 0xFFFF0000u);
          bf32[g * 4 + 2] = __builtin_bit_cast(float, bhi << 16);
          bf32[g * 4 + 3] = __builtin_bit_cast(float, bhi & 0xFFFF0000u);
        }
        float rs = 0.f;
        int pb = lr * 128 + pShift + (l15 & 7);
        #pragma unroll
        for (int tj = 0; tj < 8; tj++) {
          float p = exp2_fast(sacc[ti][tj][r] * SC + bf32[tj]);
          rs += p;
          unsigned pu = __builtin_bit_cast(unsigned, p);
          int cc = (2 * tj + (l15 >> 3)) ^ wm;
          sm[pb + cc * 8] = (u16)((pu + 0x8000u) >> 16);
        }
        lrow[ti][r] += rs;
      }

    // O += P V (wave-private P rows; V region untouched by P)
    #pragma unroll
    for (int kb = 0; kb < 4; kb++) {
      short8 pf0 = *(const short8*)&sm[(w * 32 + l15) * 128 + pShift + ((kb * 4 + quad) ^ xm) * 8];
      short8 pf1 = *(const short8*)&sm[(w * 32 + 16 + l15) * 128 + pShift + ((kb * 4 + quad) ^ xm) * 8];
      #pragma unroll
      for (int dj = 0; dj < 4; dj++) {
        short8 vf = *(const short8*)&sm[VO + (dj * 16 + l15) * 128 + ((kb * 4 + quad) ^ xm) * 8];
        oacc[0][dj] = __builtin_amdgcn_mfma_f32_16x16x32_bf16(pf0, vf, oacc[0][dj], 0, 0, 0);
        oacc[1][dj] = __builtin_amdgcn_mfma_f32_16x16x32_bf16(pf1, vf, oacc[1][dj], 0, 0, 0);
      }
    }
  }

  #pragma unroll
  for (int ti = 0; ti < 2; ti++)
    #pragma unroll
    for (int r = 0; r < 4; r++) {
      float s = lrow[ti][r];
      s += __shfl_xor(s, 1); s += __shfl_xor(s, 2);
      s += __shfl_xor(s, 4); s += __shfl_xor(s, 8);
      float inv = 1.f / s;
      int row = w * 32 + ti * 16 + quad * 4 + r;
      size_t ob = ((size_t)(b * 1024 + qt * 128 + row)) * 512 + h * 64;
      #pragma unroll
      for (int dj = 0; dj < 4; dj++)
        attn_out[ob + dj * 16 + l15] = f2bf(oacc[ti][dj][r] * inv);
    }
}

// ---------------- launch -----------------------------------------------------
extern "C" void kernel_launch(void* const* d_in, const int* in_sizes, int n_in,
                              void* d_out, int out_size, void* d_ws, size_t ws_size,
                              hipStream_t stream) {
  const float* x    = (const float*)d_in[0];
  const float* wqkv = (const float*)d_in[1];
  const float* wout = (const float*)d_in[2];
  const float* bout = (const float*)d_in[3];
  const float* btab = (const float*)d_in[4];
  const int*   rel  = (const int*)d_in[5];
  char* ws = (char*)d_ws;
  u16* xb    = (u16*)(ws + 0);
  u16* qbuf  = (u16*)(ws + 33554432);
  u16* kbuf  = (u16*)(ws + 67108864);
  u16* vtbuf = (u16*)(ws + 100663296);
  u16* biasb = (u16*)(ws + 134217728);
  u16* wqkvT = (u16*)(ws + 150994944);
  u16* woutT = (u16*)(ws + 152567808);
  float* out = (float*)d_out;

  k_cast_x  <<<8192, 256, 0, stream>>>(x, xb);
  k_prep_w  <<<4096, 256, 0, stream>>>(wqkv, wout, wqkvT, woutT);
  k_prep_bias<<<32768, 256, 0, stream>>>(rel, btab, biasb);
  k_gemm_qkv<<<dim3(12, 256), 256, 0, stream>>>(xb, wqkvT, qbuf, kbuf, vtbuf);
  k_attn2   <<<dim3(32, 64), 256, 0, stream>>>(qbuf, kbuf, vtbuf, biasb, xb);
  k_gemm_out<<<dim3(4, 256), 256, 0, stream>>>(xb, woutT, bout, out);
}